// Round 11
// baseline (450.793 us; speedup 1.0000x reference)
//
#include <hip/hip_runtime.h>

typedef _Float16 f16;
typedef _Float16 f16x2 __attribute__((ext_vector_type(2)));
typedef _Float16 f16x8 __attribute__((ext_vector_type(8)));
typedef float f32x2 __attribute__((ext_vector_type(2)));
typedef float f32x4 __attribute__((ext_vector_type(4)));

__device__ __forceinline__ float fastrcp(float x) { return __builtin_amdgcn_rcpf(x); }
__device__ __forceinline__ float sigm(float z) { return fastrcp(1.0f + __expf(-z)); }
__device__ __forceinline__ float tanhq(float z) {
  return 1.0f - 2.0f * fastrcp(1.0f + __expf(2.0f * z));
}

#define TT 512
#define NB 16
#define AUGS 184   /* [h2(64)|h1(64)|slack]; byte stride 368 = 16*23 (odd 16B multiple) */

__device__ __forceinline__ f16x8 cvt8(const float* p) {
  f32x4 a = *(const f32x4*)p;
  f32x4 b = *(const f32x4*)(p + 4);
  f16x8 r;
  #pragma unroll
  for (int i = 0; i < 4; ++i) { r[i] = (f16)a[i]; r[4 + i] = (f16)b[i]; }
  return r;
}

__global__ __launch_bounds__(1024, 4)
void lstm2_kernel(const float* __restrict__ x,
                  const float* __restrict__ Wih0, const float* __restrict__ Whh0,
                  const float* __restrict__ bih0, const float* __restrict__ bhh0,
                  const float* __restrict__ Wih1, const float* __restrict__ Whh1,
                  const float* __restrict__ bih1, const float* __restrict__ bhh1,
                  const float* __restrict__ Wlin, const float* __restrict__ blin,
                  float* __restrict__ out)
{
  __shared__ f16 lds[2 * NB * AUGS];
  f16* aug0 = lds;
  f16* aug1 = lds + NB * AUGS;

  const int tid = threadIdx.x;
  const int wv = tid >> 6;
  const int team = wv >> 3;        // 0: layer-0 stage (8 waves), 1: layer-1 stage (8 waves)
  const int uw = wv & 7;           // unit octet: units [8*uw, 8*uw+8)
  const int lane = tid & 63;
  const int m = lane & 15;         // batch column (B) / weight-row-in-tile (A)
  const int q = lane >> 4;         // k-quarter / C row group

  // Gate-pair packed tiles: tile0 rows = [gate0 units 8uw..+7 | gate1 units 8uw..+7],
  // tile1 = gates 2,3. Weight row for A-frag row m:
  const int Rw = ((m < 8) ? 0 : 56) + 8 * uw + m;     // m<8 -> gate0 row, m>=8 -> gate1 row

  f16x8 af[2][3 + 1];
  f32x4 bvt0, bvt1;
  if (team == 1) {
    af[0][0] = cvt8(&Whh1[Rw * 64 + 8 * q]);
    af[0][1] = cvt8(&Whh1[Rw * 64 + 32 + 8 * q]);
    af[0][2] = cvt8(&Wih1[Rw * 64 + 8 * q]);
    af[0][3] = cvt8(&Wih1[Rw * 64 + 32 + 8 * q]);
    af[1][0] = cvt8(&Whh1[(Rw + 128) * 64 + 8 * q]);
    af[1][1] = cvt8(&Whh1[(Rw + 128) * 64 + 32 + 8 * q]);
    af[1][2] = cvt8(&Wih1[(Rw + 128) * 64 + 8 * q]);
    af[1][3] = cvt8(&Wih1[(Rw + 128) * 64 + 32 + 8 * q]);
  } else {
    af[0][0] = cvt8(&Whh0[Rw * 64 + 8 * q]);
    af[0][1] = cvt8(&Whh0[Rw * 64 + 32 + 8 * q]);
    af[1][0] = cvt8(&Whh0[(Rw + 128) * 64 + 8 * q]);
    af[1][1] = cvt8(&Whh0[(Rw + 128) * 64 + 32 + 8 * q]);
    f16x8 t0, t1;
    #pragma unroll
    for (int i = 0; i < 8; ++i) { t0[i] = (f16)0.0f; t1[i] = (f16)0.0f; }
    if (q == 0) {
      #pragma unroll
      for (int i = 0; i < 6; ++i) {
        t0[i] = (f16)Wih0[Rw * 6 + i];
        t1[i] = (f16)Wih0[(Rw + 128) * 6 + i];
      }
    }
    af[0][2] = t0; af[1][2] = t1;
    af[0][3] = t0; af[1][3] = t1;   // unused
  }
  {
    const float* bi = (team == 1) ? bih1 : bih0;
    const float* bh = (team == 1) ? bhh1 : bhh0;
    #pragma unroll
    for (int r = 0; r < 4; ++r) {
      const int row4 = 4 * q + r;
      const int Rb = ((row4 < 8) ? 0 : 56) + 8 * uw + row4;
      bvt0[r] = bi[Rb] + bh[Rb];
      bvt1[r] = bi[Rb + 128] + bh[Rb + 128];
    }
  }

  // zero aug0 (h2(-1)=0; h1 region overwritten by prologue after barrier)
  for (int idx = tid; idx < NB * AUGS; idx += 1024) aug0[idx] = (f16)0.0f;
  __syncthreads();

  const int colb = m * AUGS;
  // units handled by this lane after the gate exchange:
  const int ubase = 8 * uw + ((q & 1) ? 4 : 0) + ((q >> 1) ? 2 : 0);

  f32x2 cst; cst[0] = 0.0f; cst[1] = 0.0f;

  // gate exchange + pointwise for 2 units (lane^32 holds the other gate pair of the same units)
  auto finish = [&](f32x4 a0, f32x4 a1, f32x2& cs) -> f16x2 {
    const bool lo = (q < 2);
    float s0 = lo ? a0[2] : a0[0];
    float s1 = lo ? a0[3] : a0[1];
    float s2 = lo ? a1[2] : a1[0];
    float s3 = lo ? a1[3] : a1[1];
    float r0 = __shfl_xor(s0, 32, 64);
    float r1 = __shfl_xor(s1, 32, 64);
    float r2 = __shfl_xor(s2, 32, 64);
    float r3 = __shfl_xor(s3, 32, 64);
    float i0 = lo ? a0[0] : r0, f0 = lo ? r0 : a0[2];
    float i1 = lo ? a0[1] : r1, f1 = lo ? r1 : a0[3];
    float g0 = lo ? a1[0] : r2, o0 = lo ? r2 : a1[2];
    float g1 = lo ? a1[1] : r3, o1 = lo ? r3 : a1[3];
    f16x2 hout;
    {
      float iv = sigm(i0), fv = sigm(f0), gv = tanhq(g0), ov = sigm(o0);
      float cn = fv * cs[0] + iv * gv; cs[0] = cn;
      hout[0] = (f16)(ov * tanhq(cn));
    }
    {
      float iv = sigm(i1), fv = sigm(f1), gv = tanhq(g1), ov = sigm(o1);
      float cn = fv * cs[1] + iv * gv; cs[1] = cn;
      hout[1] = (f16)(ov * tanhq(cn));
    }
    return hout;
  };

  // x streamed from global (L3-resident), 1-step register lookahead (team0 only)
  const float* xbase = x + (size_t)(blockIdx.x * NB + m) * (TT * 6);
  f32x2 xc0, xc1, xc2;

  if (team == 0) {
    // prologue: h1(0) = L0(x(0), h1(-1)=0): only the x K-tile
    xc0 = *(const f32x2*)(xbase + 0);
    xc1 = *(const f32x2*)(xbase + 2);
    xc2 = *(const f32x2*)(xbase + 4);
    f16x8 bx;
    bx[0] = (f16)xc0[0]; bx[1] = (f16)xc0[1];
    bx[2] = (f16)xc1[0]; bx[3] = (f16)xc1[1];
    bx[4] = (f16)xc2[0]; bx[5] = (f16)xc2[1];
    bx[6] = (f16)0.0f;   bx[7] = (f16)0.0f;
    f32x4 a0 = __builtin_amdgcn_mfma_f32_16x16x32_f16(af[0][2], bx, bvt0, 0, 0, 0);
    f32x4 a1 = __builtin_amdgcn_mfma_f32_16x16x32_f16(af[1][2], bx, bvt1, 0, 0, 0);
    f16x2 h1o = finish(a0, a1, cst);
    *(f16x2*)&aug0[colb + 64 + ubase] = h1o;
    // prime lookahead with x(1)
    xc0 = *(const f32x2*)(xbase + 6);
    xc1 = *(const f32x2*)(xbase + 8);
    xc2 = *(const f32x2*)(xbase + 10);
  }
  __syncthreads();

  f16* cur = aug0;
  f16* nxt = aug1;
  #pragma unroll 1
  for (int t = 0; t < TT - 1; ++t) {
    if (team == 1) {
      // L1(t): h2(t) = f(h2(t-1), h1(t))
      f16x8 Bh2a = *(const f16x8*)&cur[colb + 0 + 8 * q];
      f16x8 Bh2b = *(const f16x8*)&cur[colb + 32 + 8 * q];
      f16x8 Bh1a = *(const f16x8*)&cur[colb + 64 + 8 * q];
      f16x8 Bh1b = *(const f16x8*)&cur[colb + 96 + 8 * q];
      __builtin_amdgcn_s_setprio(1);
      f32x4 a0 = __builtin_amdgcn_mfma_f32_16x16x32_f16(af[0][0], Bh2a, bvt0, 0, 0, 0);
      a0 = __builtin_amdgcn_mfma_f32_16x16x32_f16(af[0][1], Bh2b, a0, 0, 0, 0);
      a0 = __builtin_amdgcn_mfma_f32_16x16x32_f16(af[0][2], Bh1a, a0, 0, 0, 0);
      a0 = __builtin_amdgcn_mfma_f32_16x16x32_f16(af[0][3], Bh1b, a0, 0, 0, 0);
      f32x4 a1 = __builtin_amdgcn_mfma_f32_16x16x32_f16(af[1][0], Bh2a, bvt1, 0, 0, 0);
      a1 = __builtin_amdgcn_mfma_f32_16x16x32_f16(af[1][1], Bh2b, a1, 0, 0, 0);
      a1 = __builtin_amdgcn_mfma_f32_16x16x32_f16(af[1][2], Bh1a, a1, 0, 0, 0);
      a1 = __builtin_amdgcn_mfma_f32_16x16x32_f16(af[1][3], Bh1b, a1, 0, 0, 0);
      __builtin_amdgcn_s_setprio(0);
      f16x2 h2o = finish(a0, a1, cst);
      *(f16x2*)&nxt[colb + ubase] = h2o;
    } else {
      // L0(t+1): h1(t+1) = f(h1(t), x(t+1)); prefetch x(t+2)
      f16x8 Bh1a = *(const f16x8*)&cur[colb + 64 + 8 * q];
      f16x8 Bh1b = *(const f16x8*)&cur[colb + 96 + 8 * q];
      const int tn = (t + 2 < TT) ? (t + 2) : (TT - 1);
      f32x2 nx0 = *(const f32x2*)(xbase + tn * 6);
      f32x2 nx1 = *(const f32x2*)(xbase + tn * 6 + 2);
      f32x2 nx2 = *(const f32x2*)(xbase + tn * 6 + 4);
      f16x8 bx;
      bx[0] = (f16)xc0[0]; bx[1] = (f16)xc0[1];
      bx[2] = (f16)xc1[0]; bx[3] = (f16)xc1[1];
      bx[4] = (f16)xc2[0]; bx[5] = (f16)xc2[1];
      bx[6] = (f16)0.0f;   bx[7] = (f16)0.0f;
      __builtin_amdgcn_s_setprio(1);
      f32x4 a0 = __builtin_amdgcn_mfma_f32_16x16x32_f16(af[0][0], Bh1a, bvt0, 0, 0, 0);
      a0 = __builtin_amdgcn_mfma_f32_16x16x32_f16(af[0][1], Bh1b, a0, 0, 0, 0);
      a0 = __builtin_amdgcn_mfma_f32_16x16x32_f16(af[0][2], bx, a0, 0, 0, 0);
      f32x4 a1 = __builtin_amdgcn_mfma_f32_16x16x32_f16(af[1][0], Bh1a, bvt1, 0, 0, 0);
      a1 = __builtin_amdgcn_mfma_f32_16x16x32_f16(af[1][1], Bh1b, a1, 0, 0, 0);
      a1 = __builtin_amdgcn_mfma_f32_16x16x32_f16(af[1][2], bx, a1, 0, 0, 0);
      __builtin_amdgcn_s_setprio(0);
      f16x2 h1o = finish(a0, a1, cst);
      *(f16x2*)&nxt[colb + 64 + ubase] = h1o;
      xc0 = nx0; xc1 = nx1; xc2 = nx2;
    }
    __syncthreads();
    f16* tmp = cur; cur = nxt; nxt = tmp;
  }

  // epilogue: L1(511) from cur{h2(510), h1(511)} -> write into nxt
  if (team == 1) {
    f16x8 Bh2a = *(const f16x8*)&cur[colb + 0 + 8 * q];
    f16x8 Bh2b = *(const f16x8*)&cur[colb + 32 + 8 * q];
    f16x8 Bh1a = *(const f16x8*)&cur[colb + 64 + 8 * q];
    f16x8 Bh1b = *(const f16x8*)&cur[colb + 96 + 8 * q];
    f32x4 a0 = __builtin_amdgcn_mfma_f32_16x16x32_f16(af[0][0], Bh2a, bvt0, 0, 0, 0);
    a0 = __builtin_amdgcn_mfma_f32_16x16x32_f16(af[0][1], Bh2b, a0, 0, 0, 0);
    a0 = __builtin_amdgcn_mfma_f32_16x16x32_f16(af[0][2], Bh1a, a0, 0, 0, 0);
    a0 = __builtin_amdgcn_mfma_f32_16x16x32_f16(af[0][3], Bh1b, a0, 0, 0, 0);
    f32x4 a1 = __builtin_amdgcn_mfma_f32_16x16x32_f16(af[1][0], Bh2a, bvt1, 0, 0, 0);
    a1 = __builtin_amdgcn_mfma_f32_16x16x32_f16(af[1][1], Bh2b, a1, 0, 0, 0);
    a1 = __builtin_amdgcn_mfma_f32_16x16x32_f16(af[1][2], Bh1a, a1, 0, 0, 0);
    a1 = __builtin_amdgcn_mfma_f32_16x16x32_f16(af[1][3], Bh1b, a1, 0, 0, 0);
    f16x2 h2o = finish(a0, a1, cst);
    *(f16x2*)&nxt[colb + ubase] = h2o;
  }
  __syncthreads();

  // final linear: out[b] = Wlin . h2(511) + blin
  if (tid < 96) {
    const int bl = tid / 6, o = tid - bl * 6;
    float s = blin[o];
    const float* wl = &Wlin[o * 64];
    #pragma unroll 8
    for (int u = 0; u < 64; ++u) s += wl[u] * (float)nxt[bl * AUGS + u];
    out[(blockIdx.x * NB + bl) * 6 + o] = s;
  }
}

extern "C" void kernel_launch(void* const* d_in, const int* in_sizes, int n_in,
                              void* d_out, int out_size, void* d_ws, size_t ws_size,
                              hipStream_t stream) {
  const float* xp    = (const float*)d_in[0];
  const float* Wih0  = (const float*)d_in[1];
  const float* Whh0  = (const float*)d_in[2];
  const float* bih0  = (const float*)d_in[3];
  const float* bhh0  = (const float*)d_in[4];
  const float* Wih1  = (const float*)d_in[5];
  const float* Whh1  = (const float*)d_in[6];
  const float* bih1  = (const float*)d_in[7];
  const float* bhh1  = (const float*)d_in[8];
  const float* Wlin  = (const float*)d_in[9];
  const float* blin  = (const float*)d_in[10];
  float* outp = (float*)d_out;

  lstm2_kernel<<<128, 1024, 0, stream>>>(xp, Wih0, Whh0, bih0, bhh0,
                                         Wih1, Whh1, bih1, bhh1,
                                         Wlin, blin, outp);
}

// Round 13
// 399.365 us; speedup vs baseline: 1.1288x; 1.1288x over previous
//
#include <hip/hip_runtime.h>

typedef _Float16 f16;
typedef _Float16 f16x4 __attribute__((ext_vector_type(4)));
typedef _Float16 f16x8 __attribute__((ext_vector_type(8)));
typedef float f32x4 __attribute__((ext_vector_type(4)));

#define LOG2E 1.4426950408889634f
#define C2LE  2.8853900817779268f

__device__ __forceinline__ float fastrcp(float x) { return __builtin_amdgcn_rcpf(x); }
__device__ __forceinline__ float fexp2(float x) { return __builtin_amdgcn_exp2f(x); }

#define TT 512
#define NB 16
/* xstage: f16 [NB][3080] raw x; dw stride 1540 (m*4 mod 32 -> 2-way = free) */
#define XBS 3080
#define XS_ELE (NB * XBS)            /* 49280 */
/* aug: [h2(64)|h1(64)|slack] stride 184 f16 = 368B (odd 16B multiple -> 2-way max) */
#define AUGS 184
#define A0OFF XS_ELE
#define A1OFF (A0OFF + NB * AUGS)
#define LDS_F16 (A1OFF + NB * AUGS)  /* 55168 */
#define LDS_BYTES (LDS_F16 * 2)      /* 110336 B */

__device__ __forceinline__ f16x8 cvt8s(const float* p, float s) {
  f32x4 a = *(const f32x4*)p;
  f32x4 b = *(const f32x4*)(p + 4);
  f16x8 r;
  #pragma unroll
  for (int i = 0; i < 4; ++i) { r[i] = (f16)(a[i] * s); r[4 + i] = (f16)(b[i] * s); }
  return r;
}

__global__ __launch_bounds__(512, 2)
void lstm2_kernel(const float* __restrict__ x,
                  const float* __restrict__ Wih0, const float* __restrict__ Whh0,
                  const float* __restrict__ bih0, const float* __restrict__ bhh0,
                  const float* __restrict__ Wih1, const float* __restrict__ Whh1,
                  const float* __restrict__ bih1, const float* __restrict__ bhh1,
                  const float* __restrict__ Wlin, const float* __restrict__ blin,
                  float* __restrict__ out)
{
  extern __shared__ f16 lds[];
  f16* xstage = lds;
  f16* aug0 = lds + A0OFF;
  f16* aug1 = lds + A1OFF;
  const unsigned int* xw = (const unsigned int*)xstage;

  const int tid = threadIdx.x;
  const int wv = tid >> 6;
  const int team = wv >> 2;        // 0: layer-0 stage, 1: layer-1 stage
  const int uw = wv & 3;           // unit group [16*uw, 16*uw+16)
  const int lane = tid & 63;
  const int m = lane & 15;         // batch column
  const int q = lane >> 4;         // k-quarter / C row group

  // ---- stationary prescaled weights (A fragments) + prescaled biases ----
  // gates i,f,o scaled by log2e; gate g by 2*log2e (exp2-direct activations)
  f16x8 af[4][4];
  f32x4 bv[4];
  #pragma unroll
  for (int g = 0; g < 4; ++g) {
    const float sg = (g == 2) ? C2LE : LOG2E;
    const int R = g * 64 + 16 * uw + m;
    if (team == 1) {
      af[g][0] = cvt8s(&Whh1[R * 64 + 8 * q], sg);
      af[g][1] = cvt8s(&Whh1[R * 64 + 32 + 8 * q], sg);
      af[g][2] = cvt8s(&Wih1[R * 64 + 8 * q], sg);
      af[g][3] = cvt8s(&Wih1[R * 64 + 32 + 8 * q], sg);
    } else {
      af[g][0] = cvt8s(&Whh0[R * 64 + 8 * q], sg);
      af[g][1] = cvt8s(&Whh0[R * 64 + 32 + 8 * q], sg);
      f16x8 t;
      #pragma unroll
      for (int i = 0; i < 8; ++i) t[i] = (f16)0.0f;
      if (q == 0) {
        #pragma unroll
        for (int i = 0; i < 6; ++i) t[i] = (f16)(Wih0[R * 6 + i] * sg);
      }
      af[g][2] = t;
      af[g][3] = t;  // unused by team 0
    }
    const float* bi = (team == 1) ? bih1 : bih0;
    const float* bh = (team == 1) ? bhh1 : bhh0;
    const int U = g * 64 + 16 * uw + 4 * q;
    #pragma unroll
    for (int r = 0; r < 4; ++r) bv[g][r] = (bi[U + r] + bh[U + r]) * sg;
  }

  // ---- stage raw x -> LDS f16 (coalesced f32x4) ----
  {
    const float* xblk = x + (size_t)blockIdx.x * (NB * TT * 6);
    #pragma unroll 1
    for (int n = 0; n < NB; ++n) {
      const float* src = xblk + n * (TT * 6);
      f16* dst = xstage + n * XBS;
      for (int idx = tid; idx < TT * 6 / 4; idx += 512) {
        f32x4 v = *(const f32x4*)&src[idx * 4];
        f16x4 h;
        #pragma unroll
        for (int i = 0; i < 4; ++i) h[i] = (f16)v[i];
        *(f16x4*)&dst[idx * 4] = h;
      }
    }
  }
  for (int idx = tid; idx < NB * AUGS; idx += 512) aug0[idx] = (f16)0.0f;
  __syncthreads();

  f32x4 cst;
  #pragma unroll
  for (int r = 0; r < 4; ++r) cst[r] = 0.0f;
  f32x4 z4;
  #pragma unroll
  for (int r = 0; r < 4; ++r) z4[r] = 0.0f;

  const int colb = m * AUGS;
  const int xdw = m * (XBS / 2);
  const int hwofs = 16 * uw + 4 * q;

  // exp2-direct, paired-rcp pointwise: trans 10 -> 7 per cell update
  auto finish = [&](const f32x4* acc, f32x4& cs) -> f16x4 {
    f16x4 ho;
    #pragma unroll
    for (int r = 0; r < 4; ++r) {
      float A = 1.0f + fexp2(-acc[0][r]);   // i (prescaled log2e)
      float B = 1.0f + fexp2(-acc[1][r]);   // f
      float G = 1.0f + fexp2(-acc[2][r]);   // g (prescaled 2*log2e)
      float O = 1.0f + fexp2(-acc[3][r]);   // o
      float d1 = fastrcp(A * B);
      float d2 = fastrcp(G * O);
      float si = d1 * B;
      float sf = d1 * A;
      float t2 = d2 * O;
      float tg = 2.0f * t2 - 1.0f;            // tanh(g)
      float so = d2 * G;
      float cn = __builtin_fmaf(sf, cs[r], si * tg);
      cs[r] = cn;
      float T = 1.0f + fexp2(cn * -C2LE);
      float th = 2.0f * fastrcp(T) - 1.0f;    // tanh(c)
      ho[r] = (f16)(so * th);
    }
    return ho;
  };

  // ---- prologue: team0 computes h1(0) = L0(x(0), 0) ----
  if (team == 0) {
    union { unsigned int u[4]; f16x8 h; } bx;
    bx.u[0] = xw[xdw + 0]; bx.u[1] = xw[xdw + 1]; bx.u[2] = xw[xdw + 2]; bx.u[3] = 0u;
    f32x4 acc[4];
    #pragma unroll
    for (int g = 0; g < 4; ++g)
      acc[g] = __builtin_amdgcn_mfma_f32_16x16x32_f16(af[g][2], bx.h, bv[g], 0, 0, 0);
    f16x4 h1o = finish(acc, cst);
    *(f16x4*)&aug0[colb + 64 + hwofs] = h1o;
  }
  __syncthreads();

  // ---- main loop: team1 L1(t) || team0 L0(t+1); 1 barrier/step ----
  f16* cur = aug0;
  f16* nxt = aug1;
  #pragma unroll 1
  for (int t = 0; t < TT - 1; ++t) {
    f16x8 Bh1a = *(const f16x8*)&cur[colb + 64 + 8 * q];
    f16x8 Bh1b = *(const f16x8*)&cur[colb + 96 + 8 * q];
    if (team == 1) {
      f16x8 Bh2a = *(const f16x8*)&cur[colb + 0 + 8 * q];
      f16x8 Bh2b = *(const f16x8*)&cur[colb + 32 + 8 * q];
      f32x4 acc[4];
      __builtin_amdgcn_s_setprio(1);
      #pragma unroll
      for (int g = 0; g < 4; ++g) {
        f32x4 p = __builtin_amdgcn_mfma_f32_16x16x32_f16(af[g][0], Bh2a, bv[g], 0, 0, 0);
        f32x4 s = __builtin_amdgcn_mfma_f32_16x16x32_f16(af[g][1], Bh2b, z4, 0, 0, 0);
        p = __builtin_amdgcn_mfma_f32_16x16x32_f16(af[g][2], Bh1a, p, 0, 0, 0);
        s = __builtin_amdgcn_mfma_f32_16x16x32_f16(af[g][3], Bh1b, s, 0, 0, 0);
        acc[g] = p + s;
      }
      __builtin_amdgcn_s_setprio(0);
      f16x4 h2o = finish(acc, cst);
      *(f16x4*)&nxt[colb + hwofs] = h2o;                 // h2(t)
    } else {
      union { unsigned int u[4]; f16x8 h; } bx;
      const int xo = xdw + 3 * (t + 1);
      bx.u[0] = xw[xo]; bx.u[1] = xw[xo + 1]; bx.u[2] = xw[xo + 2]; bx.u[3] = 0u;
      f32x4 acc[4];
      __builtin_amdgcn_s_setprio(1);
      #pragma unroll
      for (int g = 0; g < 4; ++g) {
        f32x4 p = __builtin_amdgcn_mfma_f32_16x16x32_f16(af[g][0], Bh1a, bv[g], 0, 0, 0);
        f32x4 s = __builtin_amdgcn_mfma_f32_16x16x32_f16(af[g][1], Bh1b, z4, 0, 0, 0);
        s = __builtin_amdgcn_mfma_f32_16x16x32_f16(af[g][2], bx.h, s, 0, 0, 0);
        acc[g] = p + s;
      }
      __builtin_amdgcn_s_setprio(0);
      f16x4 h1o = finish(acc, cst);
      *(f16x4*)&nxt[colb + 64 + hwofs] = h1o;            // h1(t+1)
    }
    __syncthreads();
    f16* tmp = cur; cur = nxt; nxt = tmp;
  }

  // ---- epilogue: team1 computes h2(511) into nxt ----
  if (team == 1) {
    f16x8 Bh2a = *(const f16x8*)&cur[colb + 0 + 8 * q];
    f16x8 Bh2b = *(const f16x8*)&cur[colb + 32 + 8 * q];
    f16x8 Bh1a = *(const f16x8*)&cur[colb + 64 + 8 * q];
    f16x8 Bh1b = *(const f16x8*)&cur[colb + 96 + 8 * q];
    f32x4 acc[4];
    #pragma unroll
    for (int g = 0; g < 4; ++g) {
      f32x4 p = __builtin_amdgcn_mfma_f32_16x16x32_f16(af[g][0], Bh2a, bv[g], 0, 0, 0);
      f32x4 s = __builtin_amdgcn_mfma_f32_16x16x32_f16(af[g][1], Bh2b, z4, 0, 0, 0);
      p = __builtin_amdgcn_mfma_f32_16x16x32_f16(af[g][2], Bh1a, p, 0, 0, 0);
      s = __builtin_amdgcn_mfma_f32_16x16x32_f16(af[g][3], Bh1b, s, 0, 0, 0);
      acc[g] = p + s;
    }
    f16x4 h2o = finish(acc, cst);
    *(f16x4*)&nxt[colb + hwofs] = h2o;
  }
  __syncthreads();

  // ---- final linear ----
  if (tid < 96) {
    const int bl = tid / 6, o = tid - bl * 6;
    float s = blin[o];
    const float* wl = &Wlin[o * 64];
    #pragma unroll 8
    for (int u = 0; u < 64; ++u) s += wl[u] * (float)nxt[bl * AUGS + u];
    out[(blockIdx.x * NB + bl) * 6 + o] = s;
  }
}

extern "C" void kernel_launch(void* const* d_in, const int* in_sizes, int n_in,
                              void* d_out, int out_size, void* d_ws, size_t ws_size,
                              hipStream_t stream) {
  const float* xp    = (const float*)d_in[0];
  const float* Wih0  = (const float*)d_in[1];
  const float* Whh0  = (const float*)d_in[2];
  const float* bih0  = (const float*)d_in[3];
  const float* bhh0  = (const float*)d_in[4];
  const float* Wih1  = (const float*)d_in[5];
  const float* Whh1  = (const float*)d_in[6];
  const float* bih1  = (const float*)d_in[7];
  const float* bhh1  = (const float*)d_in[8];
  const float* Wlin  = (const float*)d_in[9];
  const float* blin  = (const float*)d_in[10];
  float* outp = (float*)d_out;

  hipFuncSetAttribute(reinterpret_cast<const void*>(lstm2_kernel),
                      hipFuncAttributeMaxDynamicSharedMemorySize, LDS_BYTES);
  lstm2_kernel<<<128, 512, LDS_BYTES, stream>>>(xp, Wih0, Whh0, bih0, bhh0,
                                                Wih1, Whh1, bih1, bhh1,
                                                Wlin, blin, outp);
}

// Round 14
// 319.963 us; speedup vs baseline: 1.4089x; 1.2482x over previous
//
#include <hip/hip_runtime.h>

typedef _Float16 f16;
typedef _Float16 f16x2 __attribute__((ext_vector_type(2)));
typedef _Float16 f16x4 __attribute__((ext_vector_type(4)));
typedef _Float16 f16x8 __attribute__((ext_vector_type(8)));
typedef float f32x4 __attribute__((ext_vector_type(4)));

#define LOG2E 1.4426950408889634f
#define C2LE  2.8853900817779268f

__device__ __forceinline__ float fastrcp(float x) { return __builtin_amdgcn_rcpf(x); }
__device__ __forceinline__ float fexp2(float x) { return __builtin_amdgcn_exp2f(x); }

#define TT 512
#define NB 8
/* xstage: f16 [NB][3080] raw x; dw stride 1540 */
#define XBS 3080
#define XS_ELE (NB * XBS)            /* 24640 */
/* aug: [h2(64)|h1(64)|slack] stride 184 f16 = 368B (odd 16B multiple) */
#define AUGS 184
#define A0OFF XS_ELE
#define A1OFF (A0OFF + NB * AUGS)
#define LDS_F16 (A1OFF + NB * AUGS)  /* 27584 */
#define LDS_BYTES (LDS_F16 * 2)      /* 55168 B */

__device__ __forceinline__ f16x8 cvt8s(const float* p, float s) {
  f32x4 a = *(const f32x4*)p;
  f32x4 b = *(const f32x4*)(p + 4);
  f16x8 r;
  #pragma unroll
  for (int i = 0; i < 4; ++i) { r[i] = (f16)(a[i] * s); r[4 + i] = (f16)(b[i] * s); }
  return r;
}

__global__ __launch_bounds__(512, 2)
void lstm2_kernel(const float* __restrict__ x,
                  const float* __restrict__ Wih0, const float* __restrict__ Whh0,
                  const float* __restrict__ bih0, const float* __restrict__ bhh0,
                  const float* __restrict__ Wih1, const float* __restrict__ Whh1,
                  const float* __restrict__ bih1, const float* __restrict__ bhh1,
                  const float* __restrict__ Wlin, const float* __restrict__ blin,
                  float* __restrict__ out)
{
  extern __shared__ f16 lds[];
  f16* xstage = lds;
  f16* aug0 = lds + A0OFF;
  f16* aug1 = lds + A1OFF;
  const unsigned int* xw = (const unsigned int*)xstage;

  const int tid = threadIdx.x;
  const int wv = tid >> 6;
  const int team = wv >> 2;        // 0: layer-0 stage, 1: layer-1 stage
  const int uw = wv & 3;           // unit group [16*uw, 16*uw+16)
  const int lane = tid & 63;
  const int m = lane & 15;         // B col; valid batches are cols 0..7, cols 8..15 mirror
  const int q = lane >> 4;         // k-quarter / C row group
  const bool lohalf = (m < 8);
  const int bcol = m & 7;          // this lane's batch

  // ---- stationary prescaled weights (A fragments) + prescaled biases ----
  f16x8 af[4][4];
  f32x4 bv[4];
  #pragma unroll
  for (int g = 0; g < 4; ++g) {
    const float sg = (g == 2) ? C2LE : LOG2E;
    const int R = g * 64 + 16 * uw + m;
    if (team == 1) {
      af[g][0] = cvt8s(&Whh1[R * 64 + 8 * q], sg);
      af[g][1] = cvt8s(&Whh1[R * 64 + 32 + 8 * q], sg);
      af[g][2] = cvt8s(&Wih1[R * 64 + 8 * q], sg);
      af[g][3] = cvt8s(&Wih1[R * 64 + 32 + 8 * q], sg);
    } else {
      af[g][0] = cvt8s(&Whh0[R * 64 + 8 * q], sg);
      af[g][1] = cvt8s(&Whh0[R * 64 + 32 + 8 * q], sg);
      f16x8 t;
      #pragma unroll
      for (int i = 0; i < 8; ++i) t[i] = (f16)0.0f;
      if (q == 0) {
        #pragma unroll
        for (int i = 0; i < 6; ++i) t[i] = (f16)(Wih0[R * 6 + i] * sg);
      }
      af[g][2] = t;
      af[g][3] = t;  // unused by team 0
    }
    const float* bi = (team == 1) ? bih1 : bih0;
    const float* bh = (team == 1) ? bhh1 : bhh0;
    const int U = g * 64 + 16 * uw + 4 * q;
    #pragma unroll
    for (int r = 0; r < 4; ++r) bv[g][r] = (bi[U + r] + bh[U + r]) * sg;
  }

  // ---- stage raw x -> LDS f16 (coalesced f32x4) ----
  {
    const float* xblk = x + (size_t)blockIdx.x * (NB * TT * 6);
    #pragma unroll 1
    for (int n = 0; n < NB; ++n) {
      const float* src = xblk + n * (TT * 6);
      f16* dst = xstage + n * XBS;
      for (int idx = tid; idx < TT * 6 / 4; idx += 512) {
        f32x4 v = *(const f32x4*)&src[idx * 4];
        f16x4 h;
        #pragma unroll
        for (int i = 0; i < 4; ++i) h[i] = (f16)v[i];
        *(f16x4*)&dst[idx * 4] = h;
      }
    }
  }
  for (int idx = tid; idx < NB * AUGS; idx += 512) aug0[idx] = (f16)0.0f;
  __syncthreads();

  float cs0 = 0.0f, cs1 = 0.0f;

  const int colb = bcol * AUGS;
  const int xdw = bcol * (XBS / 2);
  // compacted row base this lane owns: units 16uw + 4q + {0,1} (lo) or {2,3} (hi)
  const int rowofs = 16 * uw + 4 * q + (lohalf ? 0 : 2);

  auto finish1 = [&](float ai, float afv, float ag, float ao, float& cs) -> f16 {
    float A = 1.0f + fexp2(-ai);
    float B = 1.0f + fexp2(-afv);
    float G = 1.0f + fexp2(-ag);
    float O = 1.0f + fexp2(-ao);
    float d1 = fastrcp(A * B);
    float d2 = fastrcp(G * O);
    float si = d1 * B;
    float sf = d1 * A;
    float tg = 2.0f * (d2 * O) - 1.0f;
    float so = d2 * G;
    float cn = __builtin_fmaf(sf, cs, si * tg);
    cs = cn;
    float T = 1.0f + fexp2(cn * -C2LE);
    float th = 2.0f * fastrcp(T) - 1.0f;
    return (f16)(so * th);
  };

  // compact 4 rows -> 2 per lane (upper half-wave takes rows {2,3} of batch m-8), then pointwise
  auto compact_finish = [&](const f32x4* acc) -> f16x2 {
    float u0[4], u1[4];
    #pragma unroll
    for (int g = 0; g < 4; ++g) {
      float h2v = __shfl_xor(acc[g][2], 8, 64);
      float h3v = __shfl_xor(acc[g][3], 8, 64);
      u0[g] = lohalf ? acc[g][0] : h2v;
      u1[g] = lohalf ? acc[g][1] : h3v;
    }
    f16x2 ho;
    ho[0] = finish1(u0[0], u0[1], u0[2], u0[3], cs0);
    ho[1] = finish1(u1[0], u1[1], u1[2], u1[3], cs1);
    return ho;
  };

  // ---- prologue: team0 computes h1(0) = L0(x(0), 0) ----
  if (team == 0) {
    union { unsigned int u[4]; f16x8 h; } bx;
    bx.u[0] = xw[xdw + 0]; bx.u[1] = xw[xdw + 1]; bx.u[2] = xw[xdw + 2]; bx.u[3] = 0u;
    f32x4 acc[4];
    #pragma unroll
    for (int g = 0; g < 4; ++g)
      acc[g] = __builtin_amdgcn_mfma_f32_16x16x32_f16(af[g][2], bx.h, bv[g], 0, 0, 0);
    f16x2 h1o = compact_finish(acc);
    *(f16x2*)&aug0[colb + 64 + rowofs] = h1o;
  }
  __syncthreads();

  // ---- main loop: team1 L1(t) || team0 L0(t+1); 1 barrier/step ----
  f16* cur = aug0;
  f16* nxt = aug1;
  #pragma unroll 1
  for (int t = 0; t < TT - 1; ++t) {
    f16x8 Bh1a = *(const f16x8*)&cur[colb + 64 + 8 * q];
    f16x8 Bh1b = *(const f16x8*)&cur[colb + 96 + 8 * q];
    if (team == 1) {
      f16x8 Bh2a = *(const f16x8*)&cur[colb + 0 + 8 * q];
      f16x8 Bh2b = *(const f16x8*)&cur[colb + 32 + 8 * q];
      f32x4 acc[4];
      __builtin_amdgcn_s_setprio(1);
      #pragma unroll
      for (int g = 0; g < 4; ++g) {
        f32x4 p = __builtin_amdgcn_mfma_f32_16x16x32_f16(af[g][0], Bh2a, bv[g], 0, 0, 0);
        p = __builtin_amdgcn_mfma_f32_16x16x32_f16(af[g][1], Bh2b, p, 0, 0, 0);
        p = __builtin_amdgcn_mfma_f32_16x16x32_f16(af[g][2], Bh1a, p, 0, 0, 0);
        acc[g] = __builtin_amdgcn_mfma_f32_16x16x32_f16(af[g][3], Bh1b, p, 0, 0, 0);
      }
      __builtin_amdgcn_s_setprio(0);
      f16x2 h2o = compact_finish(acc);
      *(f16x2*)&nxt[colb + rowofs] = h2o;                // h2(t)
    } else {
      union { unsigned int u[4]; f16x8 h; } bx;
      const int xo = xdw + 3 * (t + 1);
      bx.u[0] = xw[xo]; bx.u[1] = xw[xo + 1]; bx.u[2] = xw[xo + 2]; bx.u[3] = 0u;
      f32x4 acc[4];
      __builtin_amdgcn_s_setprio(1);
      #pragma unroll
      for (int g = 0; g < 4; ++g) {
        f32x4 p = __builtin_amdgcn_mfma_f32_16x16x32_f16(af[g][0], Bh1a, bv[g], 0, 0, 0);
        p = __builtin_amdgcn_mfma_f32_16x16x32_f16(af[g][1], Bh1b, p, 0, 0, 0);
        acc[g] = __builtin_amdgcn_mfma_f32_16x16x32_f16(af[g][2], bx.h, p, 0, 0, 0);
      }
      __builtin_amdgcn_s_setprio(0);
      f16x2 h1o = compact_finish(acc);
      *(f16x2*)&nxt[colb + 64 + rowofs] = h1o;           // h1(t+1)
    }
    __syncthreads();
    f16* tmp = cur; cur = nxt; nxt = tmp;
  }

  // ---- epilogue: team1 computes h2(511) into nxt ----
  if (team == 1) {
    f16x8 Bh2a = *(const f16x8*)&cur[colb + 0 + 8 * q];
    f16x8 Bh2b = *(const f16x8*)&cur[colb + 32 + 8 * q];
    f16x8 Bh1a = *(const f16x8*)&cur[colb + 64 + 8 * q];
    f16x8 Bh1b = *(const f16x8*)&cur[colb + 96 + 8 * q];
    f32x4 acc[4];
    #pragma unroll
    for (int g = 0; g < 4; ++g) {
      f32x4 p = __builtin_amdgcn_mfma_f32_16x16x32_f16(af[g][0], Bh2a, bv[g], 0, 0, 0);
      p = __builtin_amdgcn_mfma_f32_16x16x32_f16(af[g][1], Bh2b, p, 0, 0, 0);
      p = __builtin_amdgcn_mfma_f32_16x16x32_f16(af[g][2], Bh1a, p, 0, 0, 0);
      acc[g] = __builtin_amdgcn_mfma_f32_16x16x32_f16(af[g][3], Bh1b, p, 0, 0, 0);
    }
    f16x2 h2o = compact_finish(acc);
    *(f16x2*)&nxt[colb + rowofs] = h2o;
  }
  __syncthreads();

  // ---- final linear: out[b] = Wlin . h2(511) + blin ----
  if (tid < 48) {
    const int bl = tid / 6, o = tid - bl * 6;
    float s = blin[o];
    const float* wl = &Wlin[o * 64];
    #pragma unroll 8
    for (int u = 0; u < 64; ++u) s += wl[u] * (float)nxt[bl * AUGS + u];
    out[(blockIdx.x * NB + bl) * 6 + o] = s;
  }
}

extern "C" void kernel_launch(void* const* d_in, const int* in_sizes, int n_in,
                              void* d_out, int out_size, void* d_ws, size_t ws_size,
                              hipStream_t stream) {
  const float* xp    = (const float*)d_in[0];
  const float* Wih0  = (const float*)d_in[1];
  const float* Whh0  = (const float*)d_in[2];
  const float* bih0  = (const float*)d_in[3];
  const float* bhh0  = (const float*)d_in[4];
  const float* Wih1  = (const float*)d_in[5];
  const float* Whh1  = (const float*)d_in[6];
  const float* bih1  = (const float*)d_in[7];
  const float* bhh1  = (const float*)d_in[8];
  const float* Wlin  = (const float*)d_in[9];
  const float* blin  = (const float*)d_in[10];
  float* outp = (float*)d_out;

  hipFuncSetAttribute(reinterpret_cast<const void*>(lstm2_kernel),
                      hipFuncAttributeMaxDynamicSharedMemorySize, LDS_BYTES);
  lstm2_kernel<<<256, 512, LDS_BYTES, stream>>>(xp, Wih0, Whh0, bih0, bhh0,
                                                Wih1, Whh1, bih1, bhh1,
                                                Wlin, blin, outp);
}

// Round 15
// 293.859 us; speedup vs baseline: 1.5340x; 1.0888x over previous
//
#include <hip/hip_runtime.h>

typedef _Float16 f16;
typedef _Float16 f16x2 __attribute__((ext_vector_type(2)));
typedef _Float16 f16x4 __attribute__((ext_vector_type(4)));
typedef _Float16 f16x8 __attribute__((ext_vector_type(8)));
typedef float f32x4 __attribute__((ext_vector_type(4)));

#define LOG2E 1.4426950408889634f
#define C2LE  2.8853900817779268f

__device__ __forceinline__ float fastrcp(float x) { return __builtin_amdgcn_rcpf(x); }
__device__ __forceinline__ float fexp2(float x) { return __builtin_amdgcn_exp2f(x); }

#define TT 512
#define NB 8
/* xstage: f16 [NB][3080] raw x; dw stride 1540 */
#define XBS 3080
#define XS_ELE (NB * XBS)            /* 24640 */
/* aug: [h2(64)|h1(64)|slack] stride 184 f16 = 368B (odd 16B multiple) */
#define AUGS 184
#define A0OFF XS_ELE
#define A1OFF (A0OFF + NB * AUGS)
#define LDS_F16 (A1OFF + NB * AUGS)  /* 27584 */
#define LDS_BYTES (LDS_F16 * 2)      /* 55168 B */

__device__ __forceinline__ f16x8 cvt8s(const float* p, float s) {
  f32x4 a = *(const f32x4*)p;
  f32x4 b = *(const f32x4*)(p + 4);
  f16x8 r;
  #pragma unroll
  for (int i = 0; i < 4; ++i) { r[i] = (f16)(a[i] * s); r[4 + i] = (f16)(b[i] * s); }
  return r;
}

__global__ __launch_bounds__(512, 2)
void lstm2_kernel(const float* __restrict__ x,
                  const float* __restrict__ Wih0, const float* __restrict__ Whh0,
                  const float* __restrict__ bih0, const float* __restrict__ bhh0,
                  const float* __restrict__ Wih1, const float* __restrict__ Whh1,
                  const float* __restrict__ bih1, const float* __restrict__ bhh1,
                  const float* __restrict__ Wlin, const float* __restrict__ blin,
                  float* __restrict__ out)
{
  extern __shared__ f16 lds[];
  f16* xstage = lds;
  f16* aug0 = lds + A0OFF;
  f16* aug1 = lds + A1OFF;
  const unsigned int* xw = (const unsigned int*)xstage;

  const int tid = threadIdx.x;
  const int wv = tid >> 6;
  const int team = wv >> 2;        // 0: layer-0 stage, 1: layer-1 stage
  const int uw = wv & 3;           // unit group [16*uw, 16*uw+16)
  const int lane = tid & 63;
  const int m = lane & 15;         // B col; batches = cols 0..7, cols 8..15 mirror
  const int q = lane >> 4;         // k-quarter / C row group
  const bool lohalf = (m < 8);
  const int bcol = m & 7;          // this lane's batch

  // ---- stationary prescaled weights (A fragments) + prescaled biases ----
  f16x8 af[4][4];
  f32x4 bv[4];
  #pragma unroll
  for (int g = 0; g < 4; ++g) {
    const float sg = (g == 2) ? C2LE : LOG2E;
    const int R = g * 64 + 16 * uw + m;
    if (team == 1) {
      af[g][0] = cvt8s(&Whh1[R * 64 + 8 * q], sg);
      af[g][1] = cvt8s(&Whh1[R * 64 + 32 + 8 * q], sg);
      af[g][2] = cvt8s(&Wih1[R * 64 + 8 * q], sg);
      af[g][3] = cvt8s(&Wih1[R * 64 + 32 + 8 * q], sg);
    } else {
      af[g][0] = cvt8s(&Whh0[R * 64 + 8 * q], sg);
      af[g][1] = cvt8s(&Whh0[R * 64 + 32 + 8 * q], sg);
      f16x8 t;
      #pragma unroll
      for (int i = 0; i < 8; ++i) t[i] = (f16)0.0f;
      if (q == 0) {
        #pragma unroll
        for (int i = 0; i < 6; ++i) t[i] = (f16)(Wih0[R * 6 + i] * sg);
      }
      af[g][2] = t;
      af[g][3] = t;  // unused by team 0
    }
    const float* bi = (team == 1) ? bih1 : bih0;
    const float* bh = (team == 1) ? bhh1 : bhh0;
    const int U = g * 64 + 16 * uw + 4 * q;
    #pragma unroll
    for (int r = 0; r < 4; ++r) bv[g][r] = (bi[U + r] + bh[U + r]) * sg;
  }

  // ---- stage raw x -> LDS f16 (coalesced f32x4) ----
  {
    const float* xblk = x + (size_t)blockIdx.x * (NB * TT * 6);
    #pragma unroll 1
    for (int n = 0; n < NB; ++n) {
      const float* src = xblk + n * (TT * 6);
      f16* dst = xstage + n * XBS;
      for (int idx = tid; idx < TT * 6 / 4; idx += 512) {
        f32x4 v = *(const f32x4*)&src[idx * 4];
        f16x4 h;
        #pragma unroll
        for (int i = 0; i < 4; ++i) h[i] = (f16)v[i];
        *(f16x4*)&dst[idx * 4] = h;
      }
    }
  }
  for (int idx = tid; idx < NB * AUGS; idx += 512) aug0[idx] = (f16)0.0f;
  __syncthreads();

  float cs0 = 0.0f, cs1 = 0.0f;

  const int colb = bcol * AUGS;
  const int xdw = bcol * (XBS / 2);
  // compacted row base this lane owns: units 16uw + 4q + {0,1} (lo) or {2,3} (hi)
  const int rowofs = 16 * uw + 4 * q + (lohalf ? 0 : 2);

  auto finish1 = [&](float ai, float afv, float ag, float ao, float& cs) -> f16 {
    float A = 1.0f + fexp2(-ai);
    float B = 1.0f + fexp2(-afv);
    float G = 1.0f + fexp2(-ag);
    float O = 1.0f + fexp2(-ao);
    float d1 = fastrcp(A * B);
    float d2 = fastrcp(G * O);
    float si = d1 * B;
    float sf = d1 * A;
    float tg = 2.0f * (d2 * O) - 1.0f;
    float so = d2 * G;
    float cn = __builtin_fmaf(sf, cs, si * tg);
    cs = cn;
    float T = 1.0f + fexp2(cn * -C2LE);
    float th = 2.0f * fastrcp(T) - 1.0f;
    return (f16)(so * th);
  };

  // Mirror columns mean lanes m and m^8 hold IDENTICAL acc vectors ->
  // 4->2 row compaction is a pure register select, no cross-lane ops.
  auto compact_finish = [&](const f32x4* acc) -> f16x2 {
    float u0[4], u1[4];
    #pragma unroll
    for (int g = 0; g < 4; ++g) {
      u0[g] = lohalf ? acc[g][0] : acc[g][2];
      u1[g] = lohalf ? acc[g][1] : acc[g][3];
    }
    f16x2 ho;
    ho[0] = finish1(u0[0], u0[1], u0[2], u0[3], cs0);
    ho[1] = finish1(u1[0], u1[1], u1[2], u1[3], cs1);
    return ho;
  };

  // ---- prologue: team0 computes h1(0) = L0(x(0), 0) ----
  if (team == 0) {
    union { unsigned int u[4]; f16x8 h; } bx;
    bx.u[0] = xw[xdw + 0]; bx.u[1] = xw[xdw + 1]; bx.u[2] = xw[xdw + 2]; bx.u[3] = 0u;
    f32x4 acc[4];
    #pragma unroll
    for (int g = 0; g < 4; ++g)
      acc[g] = __builtin_amdgcn_mfma_f32_16x16x32_f16(af[g][2], bx.h, bv[g], 0, 0, 0);
    f16x2 h1o = compact_finish(acc);
    *(f16x2*)&aug0[colb + 64 + rowofs] = h1o;
  }
  __syncthreads();

  // ---- main loop: team1 L1(t) || team0 L0(t+1); 1 barrier/step ----
  f16* cur = aug0;
  f16* nxt = aug1;
  #pragma unroll 1
  for (int t = 0; t < TT - 1; ++t) {
    f16x8 Bh1a = *(const f16x8*)&cur[colb + 64 + 8 * q];
    f16x8 Bh1b = *(const f16x8*)&cur[colb + 96 + 8 * q];
    if (team == 1) {
      f16x8 Bh2a = *(const f16x8*)&cur[colb + 0 + 8 * q];
      f16x8 Bh2b = *(const f16x8*)&cur[colb + 32 + 8 * q];
      f32x4 acc[4];
      __builtin_amdgcn_s_setprio(1);
      #pragma unroll
      for (int g = 0; g < 4; ++g) {
        f32x4 p = __builtin_amdgcn_mfma_f32_16x16x32_f16(af[g][0], Bh2a, bv[g], 0, 0, 0);
        p = __builtin_amdgcn_mfma_f32_16x16x32_f16(af[g][1], Bh2b, p, 0, 0, 0);
        p = __builtin_amdgcn_mfma_f32_16x16x32_f16(af[g][2], Bh1a, p, 0, 0, 0);
        acc[g] = __builtin_amdgcn_mfma_f32_16x16x32_f16(af[g][3], Bh1b, p, 0, 0, 0);
      }
      __builtin_amdgcn_s_setprio(0);
      f16x2 h2o = compact_finish(acc);
      *(f16x2*)&nxt[colb + rowofs] = h2o;                // h2(t)
    } else {
      union { unsigned int u[4]; f16x8 h; } bx;
      const int xo = xdw + 3 * (t + 1);
      bx.u[0] = xw[xo]; bx.u[1] = xw[xo + 1]; bx.u[2] = xw[xo + 2]; bx.u[3] = 0u;
      f32x4 acc[4];
      __builtin_amdgcn_s_setprio(1);
      #pragma unroll
      for (int g = 0; g < 4; ++g) {
        f32x4 p = __builtin_amdgcn_mfma_f32_16x16x32_f16(af[g][0], Bh1a, bv[g], 0, 0, 0);
        p = __builtin_amdgcn_mfma_f32_16x16x32_f16(af[g][1], Bh1b, p, 0, 0, 0);
        acc[g] = __builtin_amdgcn_mfma_f32_16x16x32_f16(af[g][2], bx.h, p, 0, 0, 0);
      }
      __builtin_amdgcn_s_setprio(0);
      f16x2 h1o = compact_finish(acc);
      *(f16x2*)&nxt[colb + 64 + rowofs] = h1o;           // h1(t+1)
    }
    __syncthreads();
    f16* tmp = cur; cur = nxt; nxt = tmp;
  }

  // ---- epilogue: team1 computes h2(511) into nxt ----
  if (team == 1) {
    f16x8 Bh2a = *(const f16x8*)&cur[colb + 0 + 8 * q];
    f16x8 Bh2b = *(const f16x8*)&cur[colb + 32 + 8 * q];
    f16x8 Bh1a = *(const f16x8*)&cur[colb + 64 + 8 * q];
    f16x8 Bh1b = *(const f16x8*)&cur[colb + 96 + 8 * q];
    f32x4 acc[4];
    #pragma unroll
    for (int g = 0; g < 4; ++g) {
      f32x4 p = __builtin_amdgcn_mfma_f32_16x16x32_f16(af[g][0], Bh2a, bv[g], 0, 0, 0);
      p = __builtin_amdgcn_mfma_f32_16x16x32_f16(af[g][1], Bh2b, p, 0, 0, 0);
      p = __builtin_amdgcn_mfma_f32_16x16x32_f16(af[g][2], Bh1a, p, 0, 0, 0);
      acc[g] = __builtin_amdgcn_mfma_f32_16x16x32_f16(af[g][3], Bh1b, p, 0, 0, 0);
    }
    f16x2 h2o = compact_finish(acc);
    *(f16x2*)&nxt[colb + rowofs] = h2o;
  }
  __syncthreads();

  // ---- final linear: out[b] = Wlin . h2(511) + blin ----
  if (tid < 48) {
    const int bl = tid / 6, o = tid - bl * 6;
    float s = blin[o];
    const float* wl = &Wlin[o * 64];
    #pragma unroll 8
    for (int u = 0; u < 64; ++u) s += wl[u] * (float)nxt[bl * AUGS + u];
    out[(blockIdx.x * NB + bl) * 6 + o] = s;
  }
}

extern "C" void kernel_launch(void* const* d_in, const int* in_sizes, int n_in,
                              void* d_out, int out_size, void* d_ws, size_t ws_size,
                              hipStream_t stream) {
  const float* xp    = (const float*)d_in[0];
  const float* Wih0  = (const float*)d_in[1];
  const float* Whh0  = (const float*)d_in[2];
  const float* bih0  = (const float*)d_in[3];
  const float* bhh0  = (const float*)d_in[4];
  const float* Wih1  = (const float*)d_in[5];
  const float* Whh1  = (const float*)d_in[6];
  const float* bih1  = (const float*)d_in[7];
  const float* bhh1  = (const float*)d_in[8];
  const float* Wlin  = (const float*)d_in[9];
  const float* blin  = (const float*)d_in[10];
  float* outp = (float*)d_out;

  hipFuncSetAttribute(reinterpret_cast<const void*>(lstm2_kernel),
                      hipFuncAttributeMaxDynamicSharedMemorySize, LDS_BYTES);
  lstm2_kernel<<<256, 512, LDS_BYTES, stream>>>(xp, Wih0, Whh0, bih0, bhh0,
                                                Wih1, Whh1, bih1, bhh1,
                                                Wlin, blin, outp);
}